// Round 1
// baseline (550.679 us; speedup 1.0000x reference)
//
#include <hip/hip_runtime.h>
#include <hip/hip_bf16.h>

// Problem: B=8, N=4096, D=512, H=8, hk=hv=64, E=2D=1024.
// out[b,n,e] = LN_e( sum_d W[e,d] * agg[b,d,n] + bias[e] )
// agg[b,h*64+c,n] = sum_k ctx[b,h,k,c] * softmax_k(x2[b,n,h*64+k])
// ctx[b,h,k,c] = (1/Z_k) sum_n exp(x2[b,n,h*64+k]-M_k) * x1[b,n,h*64+c]

typedef short short8 __attribute__((ext_vector_type(8)));
typedef float f32x4 __attribute__((ext_vector_type(4)));
typedef unsigned int uint;
typedef unsigned short ushort;

__device__ __forceinline__ ushort f2bf(float x) {
  union { float f; uint u; } v; v.f = x;
  uint r = v.u + 0x7FFFu + ((v.u >> 16) & 1u);
  return (ushort)(r >> 16);
}

__device__ __forceinline__ void gld_lds16(const void* g, void* l) {
  __builtin_amdgcn_global_load_lds(
      (const __attribute__((address_space(1))) unsigned int*)g,
      (__attribute__((address_space(3))) unsigned int*)l, 16, 0, 0);
}

// ---------------- K1: per-(b,d) column max & sumexp over n, chunked ----------
__global__ __launch_bounds__(512) void k1_colstats(const float* __restrict__ x2,
                                                   float* __restrict__ pmax,
                                                   float* __restrict__ psum) {
  int blk = blockIdx.x;            // b*32 + ch
  int b = blk >> 5, ch = blk & 31;
  int d = threadIdx.x;             // 0..511
  const float* base = x2 + ((size_t)(b * 4096 + ch * 128) * 512) + d;
  float m = -1e30f, s = 0.f;
  for (int nn = 0; nn < 128; ++nn) {
    float v = base[(size_t)nn * 512];
    if (v > m) { s = s * __expf(m - v) + 1.f; m = v; }
    else       { s += __expf(v - m); }
  }
  int o = (b * 32 + ch) * 512 + d;
  pmax[o] = m; psum[o] = s;
}

__global__ __launch_bounds__(256) void k1b_combine(const float* __restrict__ pmax,
                                                   const float* __restrict__ psum,
                                                   float* __restrict__ M,
                                                   float* __restrict__ Z) {
  int gid = blockIdx.x * 256 + threadIdx.x;  // 0..4095 => (b,d)
  int b = gid >> 9, d = gid & 511;
  float m = -1e30f;
  for (int ch = 0; ch < 32; ++ch) m = fmaxf(m, pmax[(b * 32 + ch) * 512 + d]);
  float z = 0.f;
  for (int ch = 0; ch < 32; ++ch)
    z += psum[(b * 32 + ch) * 512 + d] * __expf(pmax[(b * 32 + ch) * 512 + d] - m);
  M[gid] = m; Z[gid] = z;
}

// ---------------- zero ctx accumulator ----------------
__global__ __launch_bounds__(256) void kzero(float* __restrict__ p) {
  p[blockIdx.x * 256 + threadIdx.x] = 0.f;
}

// ---------------- convert conv_w to bf16 ----------------
__global__ __launch_bounds__(256) void kwb(const float* __restrict__ w,
                                           ushort* __restrict__ wb) {
  int i = blockIdx.x * 256 + threadIdx.x;
  wb[i] = f2bf(w[i]);
}

// ---------------- K2: context[b,h,k,c] via MFMA over n ----------------
// grid = B*H*16 blocks, 256 thr. Block (b,h,s): tokens [s*256, s*256+256).
__global__ __launch_bounds__(256) void k2_context(const float* __restrict__ x1,
                                                  const float* __restrict__ x2,
                                                  const float* __restrict__ M,
                                                  const float* __restrict__ Z,
                                                  float* __restrict__ ctx) {
  int blk = blockIdx.x;
  int s = blk & 15, h = (blk >> 4) & 7, b = blk >> 7;
  __shared__ alignas(16) ushort Esm[64 * 72];  // [k][n] bf16, pad 8
  __shared__ alignas(16) ushort Vsm[64 * 72];  // [c][n] bf16
  int tid = threadIdx.x;
  int l = tid & 63, w = tid >> 6;
  int lr = l & 15, lg = l >> 4;
  f32x4 acc[4] = {};  // wave w owns k rows [16w,16w+16), all 64 c

  for (int sub = 0; sub < 4; ++sub) {
    int n0 = s * 256 + sub * 64;
    __syncthreads();
    #pragma unroll
    for (int i = 0; i < 16; ++i) {
      int idx = tid + i * 256;          // 0..4095
      int kk = idx & 63, nn = idx >> 6; // kk fast -> coalesced global reads
      size_t g = ((size_t)(b * 4096 + n0 + nn)) * 512 + h * 64 + kk;
      float e = __expf(x2[g] - M[b * 512 + h * 64 + kk]);
      Esm[kk * 72 + nn] = f2bf(e);
      Vsm[kk * 72 + nn] = f2bf(x1[g]);  // kk plays role of c here
    }
    __syncthreads();
    #pragma unroll
    for (int k2 = 0; k2 < 2; ++k2) {
      short8 a = *(const short8*)&Esm[(w * 16 + lr) * 72 + k2 * 32 + lg * 8];
      #pragma unroll
      for (int n = 0; n < 4; ++n) {
        short8 bb = *(const short8*)&Vsm[(n * 16 + lr) * 72 + k2 * 32 + lg * 8];
        acc[n] = __builtin_amdgcn_mfma_f32_16x16x32_bf16(a, bb, acc[n], 0, 0, 0);
      }
    }
  }
  #pragma unroll
  for (int n = 0; n < 4; ++n) {
    #pragma unroll
    for (int j = 0; j < 4; ++j) {
      int k = w * 16 + lg * 4 + j;   // m89-verified C/D mapping
      int c = n * 16 + lr;
      float val = acc[n][j] / Z[b * 512 + h * 64 + k];
      atomicAdd(&ctx[((size_t)(b * 8 + h)) * 4096 + k * 64 + c], val);
    }
  }
}

// ---------------- K3: AGG[t][d] = sum_k softmax_k(x2) * ctx[k][c], bf16 out --
// grid = B*32 blocks, 512 thr (8 waves = 8 heads). Block: 128 tokens.
__global__ __launch_bounds__(512) void k3_agg(const float* __restrict__ x2,
                                              const float* __restrict__ ctx,
                                              ushort* __restrict__ agg) {
  int blk = blockIdx.x;
  int b = blk >> 5, s2 = blk & 31;
  int tid = threadIdx.x;
  int w = tid >> 6;   // head
  int l = tid & 63;   // lane = output channel c within head
  float creg[64];
  #pragma unroll
  for (int k = 0; k < 64; ++k)
    creg[k] = ctx[((size_t)(b * 8 + w)) * 4096 + k * 64 + l];  // ctx[k][c=l]

  for (int tt = 0; tt < 128; ++tt) {
    int t = s2 * 128 + tt;
    float val = x2[((size_t)(b * 4096 + t)) * 512 + w * 64 + l];
    float m = val;
    #pragma unroll
    for (int o = 32; o > 0; o >>= 1) m = fmaxf(m, __shfl_xor(m, o));
    float e = __expf(val - m);
    float z = e;
    #pragma unroll
    for (int o = 32; o > 0; o >>= 1) z += __shfl_xor(z, o);
    float acc = 0.f;
    #pragma unroll
    for (int k = 0; k < 64; ++k) {
      float ek = __int_as_float(__builtin_amdgcn_readlane(__float_as_int(e), k));
      acc += ek * creg[k];
    }
    acc /= z;  // z uniform across lanes
    agg[((size_t)(b * 4096 + t)) * 512 + w * 64 + l] = f2bf(acc);
  }
}

// ---------------- K4: Y = AGG @ W^T + bias (bf16 MFMA, 128x128 tile) --------
__global__ __launch_bounds__(256) void k4_gemm(const ushort* __restrict__ agg,
                                               const ushort* __restrict__ wb,
                                               const float* __restrict__ conv_b,
                                               float* __restrict__ out) {
  int bm = blockIdx.x >> 3;  // 0..255  (M = 32768 / 128)
  int bn = blockIdx.x & 7;   // 0..7    (N = 1024 / 128)
  __shared__ alignas(16) ushort Asm[128 * 32];
  __shared__ alignas(16) ushort Bsm[128 * 32];
  int tid = threadIdx.x;
  int l = tid & 63, w = tid >> 6;
  int lr = l & 15, lg = l >> 4;
  int wr = (w >> 1) * 64, wc = (w & 1) * 64;
  f32x4 acc[4][4] = {};
  int rowA = bm * 128, rowB = bn * 128;
  int srow = tid >> 2;         // 0..63 within chunk
  int skel = (tid & 3) * 8;    // k element offset

  for (int k0 = 0; k0 < 512; k0 += 32) {
    __syncthreads();
    #pragma unroll
    for (int c = 0; c < 2; ++c) {
      const ushort* ga = agg + (size_t)(rowA + c * 64 + srow) * 512 + k0 + skel;
      const ushort* gb = wb  + (size_t)(rowB + c * 64 + srow) * 512 + k0 + skel;
      gld_lds16(ga, (char*)Asm + c * 4096 + w * 1024);
      gld_lds16(gb, (char*)Bsm + c * 4096 + w * 1024);
    }
    __syncthreads();
    short8 a[4], bf[4];
    #pragma unroll
    for (int m = 0; m < 4; ++m)
      a[m] = *(const short8*)&Asm[(wr + m * 16 + lr) * 32 + lg * 8];
    #pragma unroll
    for (int n = 0; n < 4; ++n)
      bf[n] = *(const short8*)&Bsm[(wc + n * 16 + lr) * 32 + lg * 8];
    #pragma unroll
    for (int m = 0; m < 4; ++m)
      #pragma unroll
      for (int n = 0; n < 4; ++n)
        acc[m][n] = __builtin_amdgcn_mfma_f32_16x16x32_bf16(a[m], bf[n], acc[m][n], 0, 0, 0);
  }

  #pragma unroll
  for (int n = 0; n < 4; ++n) {
    int col = rowB + wc + n * 16 + lr;
    float bv = conv_b[col];
    #pragma unroll
    for (int m = 0; m < 4; ++m) {
      int row0 = rowA + wr + m * 16 + lg * 4;
      #pragma unroll
      for (int j = 0; j < 4; ++j)
        out[(size_t)(row0 + j) * 1024 + col] = acc[m][n][j] + bv;
    }
  }
}

// ---------------- K5: in-place LayerNorm over e=1024 ----------------
__global__ __launch_bounds__(256) void k5_ln(float* __restrict__ out,
                                             const float* __restrict__ lnw,
                                             const float* __restrict__ lnb) {
  int t = blockIdx.x;
  int tid = threadIdx.x;
  float4 v = ((const float4*)(out + (size_t)t * 1024))[tid];
  float s  = v.x + v.y + v.z + v.w;
  float s2 = v.x * v.x + v.y * v.y + v.z * v.z + v.w * v.w;
  #pragma unroll
  for (int o = 32; o > 0; o >>= 1) { s += __shfl_xor(s, o); s2 += __shfl_xor(s2, o); }
  __shared__ float red[8];
  int w = tid >> 6, l = tid & 63;
  if (l == 0) { red[w] = s; red[4 + w] = s2; }
  __syncthreads();
  s  = red[0] + red[1] + red[2] + red[3];
  s2 = red[4] + red[5] + red[6] + red[7];
  float mean = s * (1.f / 1024.f);
  float var  = s2 * (1.f / 1024.f) - mean * mean;
  float rstd = rsqrtf(fmaxf(var, 0.f) + 1e-5f);
  float4 wv = ((const float4*)lnw)[tid];
  float4 bv = ((const float4*)lnb)[tid];
  float4 o;
  o.x = (v.x - mean) * rstd * wv.x + bv.x;
  o.y = (v.y - mean) * rstd * wv.y + bv.y;
  o.z = (v.z - mean) * rstd * wv.z + bv.z;
  o.w = (v.w - mean) * rstd * wv.w + bv.w;
  ((float4*)(out + (size_t)t * 1024))[tid] = o;
}

extern "C" void kernel_launch(void* const* d_in, const int* in_sizes, int n_in,
                              void* d_out, int out_size, void* d_ws, size_t ws_size,
                              hipStream_t stream) {
  const float* x1     = (const float*)d_in[0];
  const float* x2     = (const float*)d_in[1];
  const float* conv_w = (const float*)d_in[2];
  const float* conv_b = (const float*)d_in[3];
  const float* ln_w   = (const float*)d_in[4];
  const float* ln_b   = (const float*)d_in[5];
  float* out = (float*)d_out;

  float* ws   = (float*)d_ws;
  float* M    = ws;                 // 4096
  float* Z    = M + 4096;           // 4096
  float* pmax = Z + 4096;           // 131072 (8*32*512)
  float* psum = pmax + 131072;      // 131072
  float* ctx  = psum + 131072;      // 262144 (8*8*64*64)
  ushort* aggb = (ushort*)(ctx + 262144);  // 16777216 bf16 (32768*512)
  ushort* wbb  = aggb + 16777216;          // 524288 bf16 (1024*512)

  k1_colstats<<<256, 512, 0, stream>>>(x2, pmax, psum);
  k1b_combine<<<16, 256, 0, stream>>>(pmax, psum, M, Z);
  kzero<<<1024, 256, 0, stream>>>(ctx);            // 262144 floats
  kwb<<<2048, 256, 0, stream>>>(conv_w, wbb);      // 524288 elems
  k2_context<<<1024, 256, 0, stream>>>(x1, x2, M, Z, ctx);
  k3_agg<<<256, 512, 0, stream>>>(x2, ctx, aggb);
  k4_gemm<<<2048, 256, 0, stream>>>(aggb, wbb, conv_b, out);
  k5_ln<<<32768, 256, 0, stream>>>(out, ln_w, ln_b);
}

// Round 3
// 511.842 us; speedup vs baseline: 1.0759x; 1.0759x over previous
//
#include <hip/hip_runtime.h>
#include <hip/hip_bf16.h>

// Problem: B=8, N=4096, D=512, H=8, hk=hv=64, E=2D=1024.
// Refactor: Y[b,n,e] = sum_f W2[b,e,f] * q[b,n,f] + bias,  f = h*64+k
//   W2[b,e,h*64+k] = sum_c W[e,h*64+c] * ctx[b,h,k,c]
//   q[b,n,h*64+k]  = softmax_k over the head's 64 channels of x2
//   ctx[b,h,k,c]   = (1/Z_k) sum_n exp(x2[b,n,hk]-M_k) * x1[b,n,hc]
// Then LayerNorm over e.

typedef short short8 __attribute__((ext_vector_type(8)));
typedef float f32x4 __attribute__((ext_vector_type(4)));
typedef unsigned int uint;
typedef unsigned short ushort;

__device__ __forceinline__ ushort f2bf(float x) {
  union { float f; uint u; } v; v.f = x;
  uint r = v.u + 0x7FFFu + ((v.u >> 16) & 1u);
  return (ushort)(r >> 16);
}

__device__ __forceinline__ void gld_lds16(const void* g, void* l) {
  __builtin_amdgcn_global_load_lds(
      (const __attribute__((address_space(1))) unsigned int*)g,
      (__attribute__((address_space(3))) unsigned int*)l, 16, 0, 0);
}

// ---------------- K1: per-(b,d) column max & sumexp over n, chunked ----------
__global__ __launch_bounds__(512) void k1_colstats(const float* __restrict__ x2,
                                                   float* __restrict__ pmax,
                                                   float* __restrict__ psum) {
  int blk = blockIdx.x;            // b*32 + ch
  int b = blk >> 5, ch = blk & 31;
  int d = threadIdx.x;             // 0..511
  const float* base = x2 + ((size_t)(b * 4096 + ch * 128) * 512) + d;
  float m = -1e30f, s = 0.f;
  for (int nn = 0; nn < 128; ++nn) {
    float v = base[(size_t)nn * 512];
    if (v > m) { s = s * __expf(m - v) + 1.f; m = v; }
    else       { s += __expf(v - m); }
  }
  int o = (b * 32 + ch) * 512 + d;
  pmax[o] = m; psum[o] = s;
}

__global__ __launch_bounds__(256) void k1b_combine(const float* __restrict__ pmax,
                                                   const float* __restrict__ psum,
                                                   float* __restrict__ M,
                                                   float* __restrict__ Z) {
  int gid = blockIdx.x * 256 + threadIdx.x;  // 0..4095 => (b,d)
  int b = gid >> 9, d = gid & 511;
  float m = -1e30f;
  for (int ch = 0; ch < 32; ++ch) m = fmaxf(m, pmax[(b * 32 + ch) * 512 + d]);
  float z = 0.f;
  for (int ch = 0; ch < 32; ++ch)
    z += psum[(b * 32 + ch) * 512 + d] * __expf(pmax[(b * 32 + ch) * 512 + d] - m);
  M[gid] = m; Z[gid] = z;
}

// ---------------- zero ctx accumulator ----------------
__global__ __launch_bounds__(256) void kzero(float* __restrict__ p) {
  p[blockIdx.x * 256 + threadIdx.x] = 0.f;
}

// ---------------- K2: context[b,h,k,c] via MFMA over n ----------------
__global__ __launch_bounds__(256) void k2_context(const float* __restrict__ x1,
                                                  const float* __restrict__ x2,
                                                  const float* __restrict__ M,
                                                  const float* __restrict__ Z,
                                                  float* __restrict__ ctx) {
  int blk = blockIdx.x;
  int s = blk & 15, h = (blk >> 4) & 7, b = blk >> 7;
  __shared__ alignas(16) ushort Esm[64 * 72];  // [k][n] bf16, pad 8
  __shared__ alignas(16) ushort Vsm[64 * 72];  // [c][n] bf16
  int tid = threadIdx.x;
  int l = tid & 63, w = tid >> 6;
  int lr = l & 15, lg = l >> 4;
  f32x4 acc[4] = {};  // wave w owns k rows [16w,16w+16), all 64 c

  for (int sub = 0; sub < 4; ++sub) {
    int n0 = s * 256 + sub * 64;
    __syncthreads();
    #pragma unroll
    for (int i = 0; i < 16; ++i) {
      int idx = tid + i * 256;          // 0..4095
      int kk = idx & 63, nn = idx >> 6; // kk fast -> coalesced global reads
      size_t g = ((size_t)(b * 4096 + n0 + nn)) * 512 + h * 64 + kk;
      float e = __expf(x2[g] - M[b * 512 + h * 64 + kk]);
      Esm[kk * 72 + nn] = f2bf(e);
      Vsm[kk * 72 + nn] = f2bf(x1[g]);  // kk plays role of c here
    }
    __syncthreads();
    #pragma unroll
    for (int k2 = 0; k2 < 2; ++k2) {
      short8 a = *(const short8*)&Esm[(w * 16 + lr) * 72 + k2 * 32 + lg * 8];
      #pragma unroll
      for (int n = 0; n < 4; ++n) {
        short8 bb = *(const short8*)&Vsm[(n * 16 + lr) * 72 + k2 * 32 + lg * 8];
        acc[n] = __builtin_amdgcn_mfma_f32_16x16x32_bf16(a, bb, acc[n], 0, 0, 0);
      }
    }
  }
  #pragma unroll
  for (int n = 0; n < 4; ++n) {
    #pragma unroll
    for (int j = 0; j < 4; ++j) {
      int k = w * 16 + lg * 4 + j;   // m89-verified C/D mapping
      int c = n * 16 + lr;
      float val = acc[n][j] / Z[b * 512 + h * 64 + k];
      atomicAdd(&ctx[((size_t)(b * 8 + h)) * 4096 + k * 64 + c], val);
    }
  }
}

// ---------------- KQ: per-head channel softmax of x2 -> bf16 Q --------------
// grid = 16384, block 256: two tokens per block, 128 thr x float4 per token.
__global__ __launch_bounds__(256) void kq_softmax(const float* __restrict__ x2,
                                                  ushort* __restrict__ Q) {
  int tid = threadIdx.x;
  int tok = blockIdx.x * 2 + (tid >> 7);
  int c4 = (tid & 127) * 4;           // channel base; head = c4>>6
  float4 v = *(const float4*)(x2 + (size_t)tok * 512 + c4);
  float m = fmaxf(fmaxf(v.x, v.y), fmaxf(v.z, v.w));
  #pragma unroll
  for (int o = 1; o < 16; o <<= 1) m = fmaxf(m, __shfl_xor(m, o));  // 16-lane grp = 64 ch
  float ex = __expf(v.x - m), ey = __expf(v.y - m);
  float ez = __expf(v.z - m), ew = __expf(v.w - m);
  float z = ex + ey + ez + ew;
  #pragma unroll
  for (int o = 1; o < 16; o <<= 1) z += __shfl_xor(z, o);
  float rz = 1.f / z;
  ushort4 q;
  q.x = f2bf(ex * rz); q.y = f2bf(ey * rz);
  q.z = f2bf(ez * rz); q.w = f2bf(ew * rz);
  *(ushort4*)(Q + (size_t)tok * 512 + c4) = q;
}

// ---------------- KW2: fold ctx into conv weight, per batch -----------------
// W2[b,e,h*64+k] = sum_c W[e,h*64+c] * ctx[b,h,k,c].  grid = b(8)*h(8)*ec(8).
__global__ __launch_bounds__(256) void kw2(const float* __restrict__ W,
                                           const float* __restrict__ ctx,
                                           ushort* __restrict__ W2) {
  int blk = blockIdx.x;
  int ec = blk & 7, h = (blk >> 3) & 7, b = blk >> 6;
  __shared__ float Csm[64 * 68];   // ctx[k][c], pad 68 to spread banks
  __shared__ float Wsm[128 * 68];  // W rows e0..e0+127, cols c
  int tid = threadIdx.x;
  const float* cp = ctx + ((size_t)(b * 8 + h)) * 4096;
  #pragma unroll
  for (int i = 0; i < 4; ++i) {
    int idx = tid + i * 256, k = idx >> 4, cc = (idx & 15) * 4;
    float4 cv = *(const float4*)(cp + k * 64 + cc);
    *(float4*)(Csm + k * 68 + cc) = cv;
  }
  int e0 = ec * 128;
  #pragma unroll
  for (int i = 0; i < 8; ++i) {
    int idx = tid + i * 256, r = idx >> 4, cc = (idx & 15) * 4;
    float4 wv = *(const float4*)(W + (size_t)(e0 + r) * 512 + h * 64 + cc);
    *(float4*)(Wsm + r * 68 + cc) = wv;
  }
  __syncthreads();
  int r = tid >> 3;           // 0..31 row within set
  int kg = (tid & 7) * 8;     // 8 k-outputs per thread
  for (int rs = 0; rs < 4; ++rs) {
    int row = rs * 32 + r;
    float acc[8] = {0.f, 0.f, 0.f, 0.f, 0.f, 0.f, 0.f, 0.f};
    #pragma unroll
    for (int cc = 0; cc < 64; cc += 4) {
      float4 wv = *(const float4*)(Wsm + row * 68 + cc);
      #pragma unroll
      for (int k = 0; k < 8; ++k) {
        float4 cv = *(const float4*)(Csm + (kg + k) * 68 + cc);
        acc[k] += wv.x * cv.x + wv.y * cv.y + wv.z * cv.z + wv.w * cv.w;
      }
    }
    ushort* op = W2 + ((size_t)b << 19) + (size_t)(e0 + row) * 512 + h * 64 + kg;
    #pragma unroll
    for (int k = 0; k < 8; ++k) op[k] = f2bf(acc[k]);
  }
}

// ---------------- K4: Y[b] = Q[b] @ W2[b]^T + bias (bf16 MFMA 128x128) ------
__global__ __launch_bounds__(256) void k4_gemm(const ushort* __restrict__ Q,
                                               const ushort* __restrict__ W2,
                                               const float* __restrict__ conv_b,
                                               float* __restrict__ out) {
  int blk = blockIdx.x;
  int b = blk >> 8;            // 8 batches
  int bm = (blk >> 3) & 31;    // 4096/128
  int bn = blk & 7;            // 1024/128
  __shared__ alignas(16) ushort Asm[128 * 32];
  __shared__ alignas(16) ushort Bsm[128 * 32];
  int tid = threadIdx.x;
  int l = tid & 63, w = tid >> 6;
  int lr = l & 15, lg = l >> 4;
  int wr = (w >> 1) * 64, wc = (w & 1) * 64;
  f32x4 acc[4][4] = {};
  int rowA = b * 4096 + bm * 128;
  int rowB = bn * 128;
  const ushort* Wb = W2 + ((size_t)b << 19);
  int srow = tid >> 2;         // 0..63 within chunk
  int skel = (tid & 3) * 8;    // k element offset

  for (int k0 = 0; k0 < 512; k0 += 32) {
    __syncthreads();
    #pragma unroll
    for (int c = 0; c < 2; ++c) {
      const ushort* ga = Q  + (size_t)(rowA + c * 64 + srow) * 512 + k0 + skel;
      const ushort* gb = Wb + (size_t)(rowB + c * 64 + srow) * 512 + k0 + skel;
      gld_lds16(ga, (char*)Asm + c * 4096 + w * 1024);
      gld_lds16(gb, (char*)Bsm + c * 4096 + w * 1024);
    }
    __syncthreads();
    short8 a[4], bf[4];
    #pragma unroll
    for (int m = 0; m < 4; ++m)
      a[m] = *(const short8*)&Asm[(wr + m * 16 + lr) * 32 + lg * 8];
    #pragma unroll
    for (int n = 0; n < 4; ++n)
      bf[n] = *(const short8*)&Bsm[(wc + n * 16 + lr) * 32 + lg * 8];
    #pragma unroll
    for (int m = 0; m < 4; ++m)
      #pragma unroll
      for (int n = 0; n < 4; ++n)
        acc[m][n] = __builtin_amdgcn_mfma_f32_16x16x32_bf16(a[m], bf[n], acc[m][n], 0, 0, 0);
  }

  #pragma unroll
  for (int n = 0; n < 4; ++n) {
    int col = rowB + wc + n * 16 + lr;
    float bv = conv_b[col];
    #pragma unroll
    for (int m = 0; m < 4; ++m) {
      int row0 = rowA + wr + m * 16 + lg * 4;
      #pragma unroll
      for (int j = 0; j < 4; ++j)
        out[(size_t)(row0 + j) * 1024 + col] = acc[m][n][j] + bv;
    }
  }
}

// ---------------- K5: in-place LayerNorm over e=1024 ----------------
__global__ __launch_bounds__(256) void k5_ln(float* __restrict__ out,
                                             const float* __restrict__ lnw,
                                             const float* __restrict__ lnb) {
  int t = blockIdx.x;
  int tid = threadIdx.x;
  float4 v = ((const float4*)(out + (size_t)t * 1024))[tid];
  float s  = v.x + v.y + v.z + v.w;
  float s2 = v.x * v.x + v.y * v.y + v.z * v.z + v.w * v.w;
  #pragma unroll
  for (int o = 32; o > 0; o >>= 1) { s += __shfl_xor(s, o); s2 += __shfl_xor(s2, o); }
  __shared__ float red[8];
  int w = tid >> 6, l = tid & 63;
  if (l == 0) { red[w] = s; red[4 + w] = s2; }
  __syncthreads();
  s  = red[0] + red[1] + red[2] + red[3];
  s2 = red[4] + red[5] + red[6] + red[7];
  float mean = s * (1.f / 1024.f);
  float var  = s2 * (1.f / 1024.f) - mean * mean;
  float rstd = rsqrtf(fmaxf(var, 0.f) + 1e-5f);
  float4 wv = ((const float4*)lnw)[tid];
  float4 bv = ((const float4*)lnb)[tid];
  float4 o;
  o.x = (v.x - mean) * rstd * wv.x + bv.x;
  o.y = (v.y - mean) * rstd * wv.y + bv.y;
  o.z = (v.z - mean) * rstd * wv.z + bv.z;
  o.w = (v.w - mean) * rstd * wv.w + bv.w;
  ((float4*)(out + (size_t)t * 1024))[tid] = o;
}

extern "C" void kernel_launch(void* const* d_in, const int* in_sizes, int n_in,
                              void* d_out, int out_size, void* d_ws, size_t ws_size,
                              hipStream_t stream) {
  const float* x1     = (const float*)d_in[0];
  const float* x2     = (const float*)d_in[1];
  const float* conv_w = (const float*)d_in[2];
  const float* conv_b = (const float*)d_in[3];
  const float* ln_w   = (const float*)d_in[4];
  const float* ln_b   = (const float*)d_in[5];
  float* out = (float*)d_out;

  float* ws   = (float*)d_ws;
  float* M    = ws;                 // 4096
  float* Z    = M + 4096;           // 4096
  float* pmax = Z + 4096;           // 131072 (8*32*512)
  float* psum = pmax + 131072;      // 131072
  float* ctx  = psum + 131072;      // 262144 (8*8*64*64)
  ushort* Qb  = (ushort*)(ctx + 262144);   // 16777216 bf16 (32768*512)
  ushort* W2b = Qb + 16777216;             // 4194304 bf16 (8*1024*512)

  k1_colstats<<<256, 512, 0, stream>>>(x2, pmax, psum);
  k1b_combine<<<16, 256, 0, stream>>>(pmax, psum, M, Z);
  kzero<<<1024, 256, 0, stream>>>(ctx);            // 262144 floats
  k2_context<<<1024, 256, 0, stream>>>(x1, x2, M, Z, ctx);
  kq_softmax<<<16384, 256, 0, stream>>>(x2, Qb);
  kw2<<<512, 256, 0, stream>>>(conv_w, ctx, W2b);
  k4_gemm<<<2048, 256, 0, stream>>>(Qb, W2b, conv_b, out);
  k5_ln<<<32768, 256, 0, stream>>>(out, ln_w, ln_b);
}